// Round 4
// baseline (142.983 us; speedup 1.0000x reference)
//
#include <hip/hip_runtime.h>
#include <math.h>

// Problem constants (match reference)
constexpr int B_ = 32;
constexpr int C_ = 32;
constexpr int RES_ = 16;
constexpr int G_ = RES_ * RES_ * RES_;   // 4096
constexpr int N_ = 16384;
constexpr int H_ = 64;
// sqrt(3)/RES
__device__ constexpr float REG_THR = 0.10825317547305483f;

// float -> bf16 bits, round-to-nearest-even (values are finite here).
__device__ __forceinline__ unsigned short f2bf(float f) {
    union { float f; unsigned int u; } v; v.f = f;
    const unsigned int r = v.u + 0x7FFFu + ((v.u >> 16) & 1u);
    return (unsigned short)(r >> 16);
}

// ---------------------------------------------------------------------------
// Kernel A (fused): hx compute + per-batch scan/scatter.
//
// R11/R12 changes:
//  - s_hx stored as PACKED BF16 uints (h-pairs): LDS 42.5 KB -> 26 KB
//    (occupancy 3 -> 5 blocks/CU), FMA-phase LDS writes halved, copy-out
//    LDS reads halved. Same RNE conversion at the same values -> numerics
//    bit-identical.
//  - scatter loop CLAMPED to [0, N): under harness re-poison, garbage
//    counts previously drove a ~41 ms serial loop with OOB writes past
//    idxarr (seen in the R10 profile). Real inputs sum to exactly N and
//    are unaffected.
// ---------------------------------------------------------------------------
constexpr int TCELL = 128;    // cells per block (2 per thread)
constexpr int RS = 33;        // s_hx row stride in uints (odd: bank-safe)
constexpr int WROW = 36;      // W1 LDS row stride (floats; 144B = b128-aligned)

__global__ __launch_bounds__(256) void hx_scan_kernel(
    const float* __restrict__ x, const float* __restrict__ W1,
    const float* __restrict__ b1, const int* __restrict__ counts,
    unsigned short* __restrict__ hxb, int* __restrict__ idxarr) {
    const int b = blockIdx.y;
    const int t = threadIdx.x;

    __shared__ float __align__(16) s_w1[H_ * WROW];   // 9.2 KB
    __shared__ unsigned int s_hx[TCELL * RS];         // 16.9 KB

    if (blockIdx.x == G_ / TCELL) {
        // ---- scan + scatter (one block per batch) ----
        int* partials = (int*)s_w1;                   // 1 KB alias
        const int* cb = counts + b * G_;
        const int base = t * 16;
        int local[16];
        int s = 0;
#pragma unroll
        for (int i = 0; i < 16; ++i) { s += cb[base + i]; local[i] = s; }
        partials[t] = s;
        __syncthreads();
        for (int off = 1; off < 256; off <<= 1) {
            int v = (t >= off) ? partials[t - off] : 0;
            __syncthreads();
            partials[t] += v;
            __syncthreads();
        }
        const int prev = (t > 0) ? partials[t - 1] : 0;

        int* ib = idxarr + b * N_;
        int startk = prev;
#pragma unroll
        for (int i = 0; i < 16; ++i) {
            const int endk = prev + local[i];
            const int cell = base + i;
            const int k0 = startk > 0 ? startk : 0;        // poison-safe
            const int k1 = endk < N_ ? endk : N_;
            for (int k = k0; k < k1; ++k) ib[k] = cell;
            startk = endk;
        }
        return;
    }

    // ---- hx branch ----
    const int tile = blockIdx.x * TCELL;
    const int cell_l = t & 63;                 // lane = cell (within half-tile)
    const int hh2 = __builtin_amdgcn_readfirstlane((t >> 6) * 8); // uint idx

    // Cooperative W1 fill (2176 floats) + b1 into the row pad.
    for (int i = t; i < H_ * 34; i += 256) {
        const int r = i / 34;
        const int c = i - r * 34;
        s_w1[r * WROW + c] = W1[i];
    }
    if (t < H_) s_w1[t * WROW + 34] = b1[t];

    // Coalesced x loads for BOTH cells (issued before barrier: overlap HBM).
    const float* xb = x + ((size_t)b * C_) * G_ + tile + cell_l;
    float xv0[C_], xv1[C_];
#pragma unroll
    for (int c = 0; c < C_; ++c) {
        xv0[c] = xb[(size_t)c * G_];
        xv1[c] = xb[(size_t)c * G_ + 64];
    }
    __syncthreads();

    // 8 h-pairs per thread x 2 cells; weight-row broadcasts feed 4 FMAs/c.
    unsigned int* row0 = s_hx + cell_l * RS + hh2;
    unsigned int* row1 = s_hx + (cell_l + 64) * RS + hh2;
#pragma unroll 2
    for (int j = 0; j < 8; ++j) {
        const float* we = s_w1 + (2 * (hh2 + j) + 0) * WROW;
        const float* wo = s_w1 + (2 * (hh2 + j) + 1) * WROW;
        float e0 = we[34], q0 = wo[34];        // b1[h]
        float e1 = e0,     q1 = q0;
#pragma unroll
        for (int c = 0; c < C_; ++c) {
            e0 = fmaf(we[c], xv0[c], e0);
            q0 = fmaf(wo[c], xv0[c], q0);
            e1 = fmaf(we[c], xv1[c], e1);
            q1 = fmaf(wo[c], xv1[c], q1);
        }
        // bank = (cell*33 + k)%32 = (cell + k)%32 across lanes: conflict-free
        row0[j] = (unsigned int)f2bf(e0) | ((unsigned int)f2bf(q0) << 16);
        row1[j] = (unsigned int)f2bf(e1) | ((unsigned int)f2bf(q1) << 16);
    }
    __syncthreads();

    // Copy-out: already bf16-packed; linear coalesced uint4 stores.
    uint4* ob4 = (uint4*)(hxb + ((size_t)b * G_ + tile) * H_);
#pragma unroll
    for (int k = 0; k < 4; ++k) {
        const int L4 = t + k * 256;            // uint4 index (8 bf16)
        const int cell = L4 >> 3;
        const int base = (L4 & 7) * 4;         // uint offset within cell
        const unsigned int* s = s_hx + cell * RS + base;
        ob4[L4] = make_uint4(s[0], s[1], s[2], s[3]);
    }
}

// ---------------------------------------------------------------------------
// Kernel B: one thread per (b, n) point.  (unchanged from R10)
//   idx = idxarr[b][n]   (precomputed scatter; no LDS, no binary search)
//   W1/W2/b2 reads stay uniform-address global loads -> s_load + K$ (R9's
//   LDS table was measured +5 us: don't move them onto the LDS pipe).
// ---------------------------------------------------------------------------
__global__ __launch_bounds__(256) void point_kernel(
    const unsigned short* __restrict__ hxb, const float* __restrict__ b_rnd,
    const float* __restrict__ W1, const float* __restrict__ W2,
    const float* __restrict__ b2, const int* __restrict__ idxarr,
    float* __restrict__ out0, float* __restrict__ reg_out) {
    const int b = blockIdx.y;
    const int n = blockIdx.x * 256 + threadIdx.x;

    const int idx = idxarr[(size_t)b * N_ + n];
    const float r0 = b_rnd[((size_t)b * 2 + 0) * N_ + n];
    const float r1 = b_rnd[((size_t)b * 2 + 1) * N_ + n];
    const unsigned short* hp = hxb + ((size_t)b * G_ + idx) * H_;

    float o0 = b2[0], o1 = b2[1], o2 = b2[2];
#pragma unroll
    for (int g = 0; g < 8; ++g) {              // 8 h per group, one uint4
        const uint4 u = *(const uint4*)(hp + g * 8);
        const unsigned int uw[4] = {u.x, u.y, u.z, u.w};
        float hvv[8];
#pragma unroll
        for (int q = 0; q < 4; ++q) {
            union { unsigned int u; float f; } a, bwd;
            a.u = uw[q] << 16;                 // even h
            bwd.u = uw[q] & 0xFFFF0000u;       // odd h
            hvv[2 * q] = a.f;
            hvv[2 * q + 1] = bwd.f;
        }
#pragma unroll
        for (int j = 0; j < 8; ++j) {
            const int h = g * 8 + j;
            float hv = hvv[j];
            hv = fmaf(W1[h * 34 + 32], r0, hv);
            hv = fmaf(W1[h * 34 + 33], r1, hv);
            hv = fmaxf(hv, 0.0f);
            o0 = fmaf(W2[0 * H_ + h], hv, o0);
            o1 = fmaf(W2[1 * H_ + h], hv, o1);
            o2 = fmaf(W2[2 * H_ + h], hv, o2);
        }
    }

    const float nrm = sqrtf(o0 * o0 + o1 * o1 + o2 * o2);
    const float reg = fmaxf(nrm - REG_THR, 0.0f);

    // grid_o[k][idx] = (i_k + 0.5)/16 - 0.5, exact in fp32 from idx bits.
    o0 += (float)((idx >> 8) & 15) * 0.0625f - 0.46875f;
    o1 += (float)((idx >> 4) & 15) * 0.0625f - 0.46875f;
    o2 += (float)(idx & 15) * 0.0625f - 0.46875f;

    float* p = out0 + ((size_t)b * 3) * N_ + n;
    p[0]              = o0;
    p[N_]             = o1;
    p[2 * (size_t)N_] = o2;
    reg_out[(size_t)b * N_ + n] = reg;
}

// ---------------------------------------------------------------------------
// R12 NOTE (= R11 resubmitted after an infra-level container failure):
// hx_scan and point are each launched TWICE (idempotent: identical writes
// to identical addresses). This is a deliberate instrumented round:
//   dur_R12 - dur_R10  ~=  cost(scan + hx + point)
// to split the stubborn ~110 us between our kernels and fixed harness
// overhead (fills/gaps), which the top-5 profile view cannot show us.
// ---------------------------------------------------------------------------
extern "C" void kernel_launch(void* const* d_in, const int* in_sizes, int n_in,
                              void* d_out, int out_size, void* d_ws, size_t ws_size,
                              hipStream_t stream) {
    const float* x      = (const float*)d_in[0];  // (B, C, RES, RES, RES)
    const int*   counts = (const int*)  d_in[1];  // (B, G)
    const float* b_rnd  = (const float*)d_in[2];  // (B, 2, N)
    // d_in[3] = grid_o: unused (recomputed exactly from idx bits)
    const float* W1     = (const float*)d_in[4];  // (H, C+2)
    const float* b1     = (const float*)d_in[5];  // (H,)
    const float* W2     = (const float*)d_in[6];  // (3, H)
    const float* b2     = (const float*)d_in[7];  // (3,)

    float* out  = (float*)d_out;                  // (B, 3, N) then (B, N)
    float* rout = out + (size_t)B_ * 3 * N_;

    int* idxarr = (int*)d_ws;                     // B*N ints = 2 MB
    unsigned short* hxb =
        (unsigned short*)((char*)d_ws + (size_t)B_ * N_ * sizeof(int));
                                                  // B*G*H bf16 = 16.8 MB

    dim3 gridA(G_ / TCELL + 1, B_);               // (33, 32): +1 col = scan
    dim3 gridB(N_ / 256, B_);

    hx_scan_kernel<<<gridA, 256, 0, stream>>>(x, W1, b1, counts, hxb, idxarr);
    point_kernel<<<gridB, 256, 0, stream>>>(hxb, b_rnd, W1, W2, b2,
                                            idxarr, out, rout);
    // --- duplicated launches (measurement; outputs identical) ---
    hx_scan_kernel<<<gridA, 256, 0, stream>>>(x, W1, b1, counts, hxb, idxarr);
    point_kernel<<<gridB, 256, 0, stream>>>(hxb, b_rnd, W1, W2, b2,
                                            idxarr, out, rout);
}